// Round 7
// baseline (194.224 us; speedup 1.0000x reference)
//
#include <hip/hip_runtime.h>
#include <stdint.h>

// Problem constants
#define BATCH 16384
#define INDIM 256
#define DDIM  128
#define NEXP  8
#define ROWS  64          // batch rows per block (2 row-halves x 2 row-tiles of 16)

typedef __bf16 bfv8  __attribute__((ext_vector_type(8)));   // MFMA A/B frag: 8 bf16 = 4 VGPRs
typedef float  f32x4 __attribute__((ext_vector_type(4)));   // MFMA C/D frag

// ---------------------------------------------------------------------------
// Prep kernel: repack Wa/Wb/Ws (fp32 [8,256,128]) and Gcat (Ga16|Gb16|Gs24 pad
// to 64 rows) into bf16 MFMA B-fragment layout.
//   W frag slot t = (((st*8+e)*8+kt)*8+nt)*64+lane ; elem j = W[i][d] with
//     i = kt*32 + (lane>>4)*8 + j,  d = nt*16 + (lane&15)
//   Panel for g = st*8+e (64 KB): offset within = ((kt*8+nt)*64+lane)*8 elems.
// ---------------------------------------------------------------------------
__global__ void prep_kernel(const float* __restrict__ Wa, const float* __restrict__ Wb,
                            const float* __restrict__ Ws, const float* __restrict__ Ga,
                            const float* __restrict__ Gb, const float* __restrict__ Gs,
                            __bf16* __restrict__ wp, __bf16* __restrict__ gp) {
    int t = blockIdx.x * 256 + threadIdx.x;
    const int NW = 3 * 8 * 8 * 8 * 64;   // 98304 W-frag slots
    if (t < NW) {
        int lane = t & 63, nt = (t >> 6) & 7, kt = (t >> 9) & 7, e = (t >> 12) & 7, st = t >> 15;
        const float* W = (st == 0) ? Wa : (st == 1) ? Wb : Ws;
        int d  = nt * 16 + (lane & 15);
        int i0 = kt * 32 + (lane >> 4) * 8;
        __bf16* o = wp + (size_t)t * 8;
#pragma unroll
        for (int j = 0; j < 8; j++)
            o[j] = (__bf16)W[(size_t)(e * 256 + i0 + j) * 128 + d];
    } else if (t < NW + 2048) {
        int t2 = t - NW;
        int lane = t2 & 63, nt = (t2 >> 6) & 3, kt = t2 >> 8;
        int g  = nt * 16 + (lane & 15);
        int k0 = kt * 32 + (lane >> 4) * 8;
        __bf16* o = gp + (size_t)t2 * 8;
#pragma unroll
        for (int j = 0; j < 8; j++) {
            int k = k0 + j;
            float v = 0.f;
            if (g < 16)      v = Ga[g * 256 + k];
            else if (g < 32) v = Gb[(g - 16) * 256 + k];
            else if (g < 56) v = Gs[(g - 32) * 256 + k];
            o[j] = (__bf16)v;
        }
    }
}

// Load A fragments (2 row-tiles x 8 k-tiles) for one x stream, fp32->bf16.
__device__ __forceinline__ void load_afr(const float* __restrict__ x, int rb,
                                         int l16, int quad, bfv8 afr[2][8]) {
#pragma unroll
    for (int mt = 0; mt < 2; mt++) {
        const float* xr = x + (size_t)(rb + mt * 16 + l16) * INDIM;
#pragma unroll
        for (int kt = 0; kt < 8; kt++) {
            f32x4 lo = *(const f32x4*)(xr + kt * 32 + quad * 8);
            f32x4 hi = *(const f32x4*)(xr + kt * 32 + quad * 8 + 4);
            bfv8 a;
            a[0] = (__bf16)lo[0]; a[1] = (__bf16)lo[1]; a[2] = (__bf16)lo[2]; a[3] = (__bf16)lo[3];
            a[4] = (__bf16)hi[0]; a[5] = (__bf16)hi[1]; a[6] = (__bf16)hi[2]; a[7] = (__bf16)hi[3];
            afr[mt][kt] = a;
        }
    }
}

// Async global->LDS DMA: gptr is PER-LANE (16 B each), lptr is WAVE-UNIFORM
// base; hardware deposits lane's 16 B at lptr + lane*16.
__device__ __forceinline__ void async_load16(const __bf16* g, __bf16* l) {
    __builtin_amdgcn_global_load_lds(
        (const __attribute__((address_space(1))) uint32_t*)g,
        (__attribute__((address_space(3))) uint32_t*)l, 16, 0, 0);
}

// ---------------------------------------------------------------------------
// Main fused kernel. Grid 256 blocks (1/CU) x 640 threads:
//   waves 0..7  = consumers: (wr=w>>2: rows 32wr+), (wc=w&3: cols 32wc+)
//   waves 8..9  = producers: DMA expert B-panels (64 KB each) into a 2-slot
//                 LDS double buffer; wave8 = even panels, wave9 = odd panels.
// Sync is per-panel LDS flags (acquire/release), NO block barrier in K-loop:
// consumers never issue a global load for B, so no vmcnt drain ever blocks
// the MFMA stream (the R3-R6 latency-serialization fix).
// LDS: Bbuf 128 KB + wT 16 KB + flags; lgt (phase 1 only) aliases Bbuf[0].
// ---------------------------------------------------------------------------
__launch_bounds__(640, 2)
__global__ void ple_kernel(const float* __restrict__ xa, const float* __restrict__ xb,
                           const float* __restrict__ xs,
                           const float* __restrict__ ba, const float* __restrict__ bb,
                           const float* __restrict__ bs,
                           const __bf16* __restrict__ wp, const __bf16* __restrict__ gp,
                           float* __restrict__ out) {
    __shared__ __bf16 Bbuf[2][32768];   // 128 KB: slot s, panel layout (kt*8+nt)*512+lane*8
    __shared__ float  wT[64 * ROWS];    // 16 KB: softmax weights [gate][row]
    __shared__ int    ready[24];        // producer -> consumer: panel g staged
    __shared__ int    done[24];         // consumer -> producer: 8 waves finished panel g

    const int tid  = threadIdx.x;
    const int w    = tid >> 6;          // wave id 0..9
    const int lane = tid & 63;
    const int quad = lane >> 4;
    const int l16  = lane & 15;
    const int r0   = blockIdx.x * ROWS;

    float* lgt = (float*)&Bbuf[0][0];   // 16 KB alias; dead after phase 1

    if (tid < 24) { ready[tid] = 0; done[tid] = 0; }

    // ---- Phase 1: gate logits via MFMA (consumer waves only) ----
    // wave w<8: gate n-tile nt = w>>1 (stream a/b/s/s), row half mh=(w&1)*32.
    if (w < 8) {
        const int nt = w >> 1;
        const int mh = (w & 1) * 32;
        const float* x = (nt == 0) ? xa : (nt == 1) ? xb : xs;  // wave-uniform
        bfv8 afr[2][8];
        load_afr(x, r0 + mh, l16, quad, afr);
        f32x4 acc0 = {0.f, 0.f, 0.f, 0.f}, acc1 = {0.f, 0.f, 0.f, 0.f};
#pragma unroll
        for (int kt = 0; kt < 8; kt++) {
            bfv8 g = *(const bfv8*)(gp + ((size_t)(kt * 4 + nt) * 64 + lane) * 8);
            acc0 = __builtin_amdgcn_mfma_f32_16x16x32_bf16(afr[0][kt], g, acc0, 0, 0, 0);
            acc1 = __builtin_amdgcn_mfma_f32_16x16x32_bf16(afr[1][kt], g, acc1, 0, 0, 0);
        }
#pragma unroll
        for (int r = 0; r < 4; r++) {
            lgt[(mh + quad * 4 + r) * 64 + nt * 16 + l16]      = acc0[r];
            lgt[(mh + 16 + quad * 4 + r) * 64 + nt * 16 + l16] = acc1[r];
        }
    }
    __syncthreads();

    // ---- softmax per row, 3 gate groups; store transposed ----
    if (tid < ROWS) {
        const float* L = lgt + tid * 64;
#pragma unroll
        for (int gi = 0; gi < 3; gi++) {
            const int base = (gi == 0) ? 0 : (gi == 1 ? 16 : 32);
            const int cnt  = (gi == 2) ? 24 : 16;
            float m = -1e30f;
            for (int k = 0; k < cnt; k++) m = fmaxf(m, L[base + k]);
            float s = 0.f;
            for (int k = 0; k < cnt; k++) s += __expf(L[base + k] - m);
            float inv = 1.f / s;
            for (int k = 0; k < cnt; k++) wT[(base + k) * ROWS + tid] = __expf(L[base + k] - m) * inv;
        }
    }
    __syncthreads();   // last block barrier; lgt (Bbuf alias) dead from here

    if (w >= 8) {
        // ================= PRODUCER waves =================
        const int pid = w - 8;              // 0: even panels, 1: odd panels
#pragma unroll 1
        for (int g = pid; g < 24; g += 2) {
            if (g >= 2) {
                while (__hip_atomic_load(&done[g - 2], __ATOMIC_ACQUIRE,
                                         __HIP_MEMORY_SCOPE_WORKGROUP) < 8)
                    __builtin_amdgcn_s_sleep(2);
            }
            const __bf16* gsrc = wp + (size_t)g * 32768 + (size_t)lane * 8;  // per-lane
            __bf16* ldst = &Bbuf[g & 1][0];                                  // uniform
#pragma unroll
            for (int c = 0; c < 64; c++)
                async_load16(gsrc + (size_t)c * 512, ldst + c * 512);
            __asm__ volatile("s_waitcnt vmcnt(0)" ::: "memory");
            __hip_atomic_store(&ready[g], 1, __ATOMIC_RELEASE,
                               __HIP_MEMORY_SCOPE_WORKGROUP);
        }
        return;
    }

    // ================= CONSUMER waves =================
    const int wr = w >> 2;              // row half 0..1
    const int wc = w & 3;               // col group 0..3
    const int mb = wr * 32;             // local row base

    float o[3][2][2][4];                // [out][mt][ntl][reg] = 48 VGPRs
#pragma unroll
    for (int oi = 0; oi < 3; oi++)
#pragma unroll
        for (int mt = 0; mt < 2; mt++)
#pragma unroll
            for (int ntl = 0; ntl < 2; ntl++)
#pragma unroll
                for (int r = 0; r < 4; r++) o[oi][mt][ntl][r] = 0.f;

#define FOLD(oi, gbase)                                                                \
    {                                                                                  \
        _Pragma("unroll")                                                              \
        for (int mt = 0; mt < 2; mt++) {                                               \
            f32x4 wv = *(const f32x4*)(wT + (gbase + eb) * ROWS + mb + mt * 16 + quad * 4); \
            _Pragma("unroll")                                                          \
            for (int ntl = 0; ntl < 2; ntl++)                                          \
                _Pragma("unroll")                                                      \
                for (int r = 0; r < 4; r++)                                            \
                    o[oi][mt][ntl][r] += wv[r] * acc[mt][ntl][r];                      \
        }                                                                              \
    }

    bfv8 afr[2][8];                     // A frags for current stream (64 VGPRs)

#pragma unroll 1
    for (int g = 0; g < 24; g++) {
        const int st = g >> 3;
        const int eb = g & 7;
        if ((g & 7) == 0) {
            const float* x = (st == 0) ? xa : (st == 1) ? xb : xs;
            load_afr(x, r0 + mb, l16, quad, afr);
        }
        // wait for panel g staged in LDS
        while (__hip_atomic_load(&ready[g], __ATOMIC_ACQUIRE,
                                 __HIP_MEMORY_SCOPE_WORKGROUP) == 0)
            __builtin_amdgcn_s_sleep(1);

        const __bf16* bbase = &Bbuf[g & 1][0] + (size_t)(2 * wc) * 512 + (size_t)lane * 8;

        f32x4 acc[2][2];
#pragma unroll
        for (int mt = 0; mt < 2; mt++)
#pragma unroll
            for (int ntl = 0; ntl < 2; ntl++) { f32x4 z = {0.f, 0.f, 0.f, 0.f}; acc[mt][ntl] = z; }

#pragma unroll
        for (int kt = 0; kt < 8; kt++) {
            bfv8 c0 = *(const bfv8*)(bbase + (size_t)kt * 4096);
            bfv8 c1 = *(const bfv8*)(bbase + (size_t)kt * 4096 + 512);
            acc[0][0] = __builtin_amdgcn_mfma_f32_16x16x32_bf16(afr[0][kt], c0, acc[0][0], 0, 0, 0);
            acc[1][0] = __builtin_amdgcn_mfma_f32_16x16x32_bf16(afr[1][kt], c0, acc[1][0], 0, 0, 0);
            acc[0][1] = __builtin_amdgcn_mfma_f32_16x16x32_bf16(afr[0][kt], c1, acc[0][1], 0, 0, 0);
            acc[1][1] = __builtin_amdgcn_mfma_f32_16x16x32_bf16(afr[1][kt], c1, acc[1][1], 0, 0, 0);
        }

        // release the buffer slot (RELEASE orders after the ds_reads above)
        if (lane == 0)
            __hip_atomic_fetch_add(&done[g], 1, __ATOMIC_RELEASE,
                                   __HIP_MEMORY_SCOPE_WORKGROUP);

        // bias (per output column)
        const float* bias = (st == 0) ? ba : (st == 1) ? bb : bs;
        float b0 = bias[eb * 128 + wc * 32 + l16];
        float b1 = bias[eb * 128 + wc * 32 + 16 + l16];
#pragma unroll
        for (int mt = 0; mt < 2; mt++)
#pragma unroll
            for (int r = 0; r < 4; r++) { acc[mt][0][r] += b0; acc[mt][1][r] += b1; }

        // gated fold. Gate table rows: a:0-15, b:16-31, s:32-55.
        // out_a = cat(ea,es): ea->e, es->8+e ; out_b = cat(eb,es): eb->16+e, es->24+e
        // out_s = cat(ea,eb,es): ea->32+e, eb->40+e, es->48+e
        if (st == 0)      { FOLD(0, 0);  FOLD(2, 32); }
        else if (st == 1) { FOLD(1, 16); FOLD(2, 40); }
        else              { FOLD(0, 8);  FOLD(1, 24); FOLD(2, 48); }
    }
#undef FOLD

    // ---- epilogue: store 3 outputs; wave covers rows mb.., cols 32wc.. ----
#pragma unroll
    for (int oi = 0; oi < 3; oi++) {
        float* ob = out + (size_t)oi * BATCH * DDIM;
#pragma unroll
        for (int mt = 0; mt < 2; mt++)
#pragma unroll
            for (int r = 0; r < 4; r++) {
                int row = r0 + mb + mt * 16 + quad * 4 + r;
#pragma unroll
                for (int ntl = 0; ntl < 2; ntl++)
                    ob[(size_t)row * DDIM + wc * 32 + ntl * 16 + l16] = o[oi][mt][ntl][r];
            }
    }
}

extern "C" void kernel_launch(void* const* d_in, const int* in_sizes, int n_in,
                              void* d_out, int out_size, void* d_ws, size_t ws_size,
                              hipStream_t stream) {
    const float* xa = (const float*)d_in[0];
    const float* xb = (const float*)d_in[1];
    const float* xs = (const float*)d_in[2];
    const float* Wa = (const float*)d_in[3];
    const float* ba = (const float*)d_in[4];
    const float* Wb = (const float*)d_in[5];
    const float* bb = (const float*)d_in[6];
    const float* Ws = (const float*)d_in[7];
    const float* bs = (const float*)d_in[8];
    const float* Ga = (const float*)d_in[9];
    const float* Gb = (const float*)d_in[10];
    const float* Gs = (const float*)d_in[11];

    __bf16* wp = (__bf16*)d_ws;                 // 1.5 MB packed expert weights
    __bf16* gp = wp + 3 * 8 * 8 * 8 * 64 * 8;   // packed gate matrix

    prep_kernel<<<392, 256, 0, stream>>>(Wa, Wb, Ws, Ga, Gb, Gs, wp, gp);
    ple_kernel<<<BATCH / ROWS, 640, 0, stream>>>(xa, xb, xs, ba, bb, bs, wp, gp, (float*)d_out);
}

// Round 8
// 176.381 us; speedup vs baseline: 1.1012x; 1.1012x over previous
//
#include <hip/hip_runtime.h>
#include <stdint.h>

// Problem constants
#define BATCH 16384
#define INDIM 256
#define DDIM  128
#define NEXP  8
#define ROWS  64          // batch rows per block (2 row-halves x 2 row-tiles of 16)

typedef __bf16 bfv8  __attribute__((ext_vector_type(8)));   // MFMA A/B frag: 8 bf16 = 4 VGPRs
typedef float  f32x4 __attribute__((ext_vector_type(4)));   // MFMA C/D frag

// ---------------------------------------------------------------------------
// Prep kernel: repack Wa/Wb/Ws (fp32 [8,256,128]) and Gcat (Ga16|Gb16|Gs24 pad
// to 64 rows) into bf16 MFMA B-fragment layout.
//   W frag slot t = (((st*8+e)*8+kt)*8+nt)*64+lane ; elem j = W[i][d] with
//     i = kt*32 + (lane>>4)*8 + j,  d = nt*16 + (lane&15)
//   Panel g = st*8+e is 64 KB: elem offset = (kt*8+nt)*512 + lane*8.
// ---------------------------------------------------------------------------
__global__ void prep_kernel(const float* __restrict__ Wa, const float* __restrict__ Wb,
                            const float* __restrict__ Ws, const float* __restrict__ Ga,
                            const float* __restrict__ Gb, const float* __restrict__ Gs,
                            __bf16* __restrict__ wp, __bf16* __restrict__ gp) {
    int t = blockIdx.x * 256 + threadIdx.x;
    const int NW = 3 * 8 * 8 * 8 * 64;   // 98304 W-frag slots
    if (t < NW) {
        int lane = t & 63, nt = (t >> 6) & 7, kt = (t >> 9) & 7, e = (t >> 12) & 7, st = t >> 15;
        const float* W = (st == 0) ? Wa : (st == 1) ? Wb : Ws;
        int d  = nt * 16 + (lane & 15);
        int i0 = kt * 32 + (lane >> 4) * 8;
        __bf16* o = wp + (size_t)t * 8;
#pragma unroll
        for (int j = 0; j < 8; j++)
            o[j] = (__bf16)W[(size_t)(e * 256 + i0 + j) * 128 + d];
    } else if (t < NW + 2048) {
        int t2 = t - NW;
        int lane = t2 & 63, nt = (t2 >> 6) & 3, kt = t2 >> 8;
        int g  = nt * 16 + (lane & 15);
        int k0 = kt * 32 + (lane >> 4) * 8;
        __bf16* o = gp + (size_t)t2 * 8;
#pragma unroll
        for (int j = 0; j < 8; j++) {
            int k = k0 + j;
            float v = 0.f;
            if (g < 16)      v = Ga[g * 256 + k];
            else if (g < 32) v = Gb[(g - 16) * 256 + k];
            else if (g < 56) v = Gs[(g - 32) * 256 + k];
            o[j] = (__bf16)v;
        }
    }
}

// Load A fragments (2 row-tiles x 8 k-tiles) for one x stream, fp32->bf16.
__device__ __forceinline__ void load_afr(const float* __restrict__ x, int rb,
                                         int l16, int quad, bfv8 afr[2][8]) {
#pragma unroll
    for (int mt = 0; mt < 2; mt++) {
        const float* xr = x + (size_t)(rb + mt * 16 + l16) * INDIM;
#pragma unroll
        for (int kt = 0; kt < 8; kt++) {
            f32x4 lo = *(const f32x4*)(xr + kt * 32 + quad * 8);
            f32x4 hi = *(const f32x4*)(xr + kt * 32 + quad * 8 + 4);
            bfv8 a;
            a[0] = (__bf16)lo[0]; a[1] = (__bf16)lo[1]; a[2] = (__bf16)lo[2]; a[3] = (__bf16)lo[3];
            a[4] = (__bf16)hi[0]; a[5] = (__bf16)hi[1]; a[6] = (__bf16)hi[2]; a[7] = (__bf16)hi[3];
            afr[mt][kt] = a;
        }
    }
}

// Async global->LDS DMA: gptr per-lane (16 B each); lptr wave-uniform base,
// HW deposits lane's 16 B at lptr + lane*16.
__device__ __forceinline__ void async_load16(const __bf16* g, __bf16* l) {
    __builtin_amdgcn_global_load_lds(
        (const __attribute__((address_space(1))) uint32_t*)g,
        (__attribute__((address_space(3))) uint32_t*)l, 16, 0, 0);
}

// ---------------------------------------------------------------------------
// Main fused kernel. Grid 256 blocks (1/CU) x 512 threads (8 waves).
// Block = 64 rows x 128 cols. Wave (wr=w>>2, wc=w&3): rows [32wr,+32),
// cols [32wc,+32).
// K-loop = 24 expert panels, m97-style barrier pipeline: while computing
// panel g from LDS buf[g&1], ALL waves DMA panel g+1 into buf[(g+1)&1]
// (8 global_load_lds dwordx4 per wave; each B cacheline fetched ONCE per CU
// — the R3-R7 invariant cost was duplicated per-CU line transactions).
// One __syncthreads per panel, no flag handshakes.
// LDS: Bbuf 128 KB + wT 16 KB = 144 KB; lgt (phase 1) aliases Bbuf[1].
// ---------------------------------------------------------------------------
__launch_bounds__(512, 2)
__global__ void ple_kernel(const float* __restrict__ xa, const float* __restrict__ xb,
                           const float* __restrict__ xs,
                           const float* __restrict__ ba, const float* __restrict__ bb,
                           const float* __restrict__ bs,
                           const __bf16* __restrict__ wp, const __bf16* __restrict__ gp,
                           float* __restrict__ out) {
    __shared__ __bf16 Bbuf[2][32768];   // 128 KB; panel layout (kt*8+nt)*512+lane*8
    __shared__ float  wT[64 * ROWS];    // 16 KB: softmax weights [gate][row]

    const int tid  = threadIdx.x;
    const int w    = tid >> 6;          // wave id 0..7
    const int lane = tid & 63;
    const int quad = lane >> 4;
    const int l16  = lane & 15;
    const int r0   = blockIdx.x * ROWS;

    float* lgt = (float*)&Bbuf[1][0];   // 16 KB alias; dead after softmax

    bfv8 afr[2][8];                     // A frags (64 VGPRs)

    // ---- Phase 1: gate logits via MFMA ----
    // wave w: gate n-tile nt = w>>1 (stream a/b/s/s), row half mh = (w&1)*32.
    {
        const int nt = w >> 1;
        const int mh = (w & 1) * 32;
        const float* x = (nt == 0) ? xa : (nt == 1) ? xb : xs;  // wave-uniform
        load_afr(x, r0 + mh, l16, quad, afr);
        f32x4 acc0 = {0.f, 0.f, 0.f, 0.f}, acc1 = {0.f, 0.f, 0.f, 0.f};
#pragma unroll
        for (int kt = 0; kt < 8; kt++) {
            bfv8 g = *(const bfv8*)(gp + ((size_t)(kt * 4 + nt) * 64 + lane) * 8);
            acc0 = __builtin_amdgcn_mfma_f32_16x16x32_bf16(afr[0][kt], g, acc0, 0, 0, 0);
            acc1 = __builtin_amdgcn_mfma_f32_16x16x32_bf16(afr[1][kt], g, acc1, 0, 0, 0);
        }
#pragma unroll
        for (int r = 0; r < 4; r++) {
            lgt[(mh + quad * 4 + r) * 64 + nt * 16 + l16]      = acc0[r];
            lgt[(mh + 16 + quad * 4 + r) * 64 + nt * 16 + l16] = acc1[r];
        }
    }
    __syncthreads();

    // ---- stage panel 0 into Bbuf[0] (overlaps softmax below) ----
    {
        const __bf16* src = wp + (size_t)w * 4096 + (size_t)lane * 8;
        __bf16* dst = &Bbuf[0][w * 4096];
#pragma unroll
        for (int c = 0; c < 8; c++)
            async_load16(src + (size_t)c * 512, dst + c * 512);
    }

    // ---- softmax per row, 3 gate groups; store transposed (reads lgt=Bbuf[1]) ----
    if (tid < ROWS) {
        const float* L = lgt + tid * 64;
#pragma unroll
        for (int gi = 0; gi < 3; gi++) {
            const int base = (gi == 0) ? 0 : (gi == 1 ? 16 : 32);
            const int cnt  = (gi == 2) ? 24 : 16;
            float m = -1e30f;
            for (int k = 0; k < cnt; k++) m = fmaxf(m, L[base + k]);
            float s = 0.f;
            for (int k = 0; k < cnt; k++) s += __expf(L[base + k] - m);
            float inv = 1.f / s;
            for (int k = 0; k < cnt; k++) wT[(base + k) * ROWS + tid] = __expf(L[base + k] - m) * inv;
        }
    }
    __syncthreads();   // drains panel-0 DMA too; lgt dead from here

    // ---- Phase 2: 24-panel barrier-pipelined K-loop ----
    const int wr = w >> 2;              // row half
    const int wc = w & 3;               // col group
    const int mb = wr * 32;             // local row base

    float o[3][2][2][4];                // [out][mt][ntl][reg] = 48 VGPRs
#pragma unroll
    for (int oi = 0; oi < 3; oi++)
#pragma unroll
        for (int mt = 0; mt < 2; mt++)
#pragma unroll
            for (int ntl = 0; ntl < 2; ntl++)
#pragma unroll
                for (int r = 0; r < 4; r++) o[oi][mt][ntl][r] = 0.f;

#define FOLD(oi, gbase)                                                                \
    {                                                                                  \
        _Pragma("unroll")                                                              \
        for (int mt = 0; mt < 2; mt++) {                                               \
            f32x4 wv = *(const f32x4*)(wT + (gbase + eb) * ROWS + mb + mt * 16 + quad * 4); \
            _Pragma("unroll")                                                          \
            for (int ntl = 0; ntl < 2; ntl++)                                          \
                _Pragma("unroll")                                                      \
                for (int r = 0; r < 4; r++)                                            \
                    o[oi][mt][ntl][r] += wv[r] * acc[mt][ntl][r];                      \
        }                                                                              \
    }

#pragma unroll 1
    for (int g = 0; g < 24; g++) {
        const int st = g >> 3;
        const int eb = g & 7;

        if (eb == 0) {                  // stream boundary: refresh A registers
            const float* x = (st == 0) ? xa : (st == 1) ? xb : xs;
            load_afr(x, r0 + mb, l16, quad, afr);
        }

        // DMA panel g+1 into the other buffer (wave w stages kt=w slice)
        if (g < 23) {
            const __bf16* src = wp + (size_t)(g + 1) * 32768 + (size_t)w * 4096
                                + (size_t)lane * 8;
            __bf16* dst = &Bbuf[(g + 1) & 1][w * 4096];
#pragma unroll
            for (int c = 0; c < 8; c++)
                async_load16(src + (size_t)c * 512, dst + c * 512);
        }

        // compute panel g from LDS
        const __bf16* bbase = &Bbuf[g & 1][(2 * wc) * 512] + (size_t)lane * 8;
        f32x4 acc[2][2];
#pragma unroll
        for (int mt = 0; mt < 2; mt++)
#pragma unroll
            for (int ntl = 0; ntl < 2; ntl++) { f32x4 z = {0.f, 0.f, 0.f, 0.f}; acc[mt][ntl] = z; }

#pragma unroll
        for (int kt = 0; kt < 8; kt++) {
            bfv8 c0 = *(const bfv8*)(bbase + (size_t)kt * 4096);
            bfv8 c1 = *(const bfv8*)(bbase + (size_t)kt * 4096 + 512);
            acc[0][0] = __builtin_amdgcn_mfma_f32_16x16x32_bf16(afr[0][kt], c0, acc[0][0], 0, 0, 0);
            acc[1][0] = __builtin_amdgcn_mfma_f32_16x16x32_bf16(afr[1][kt], c0, acc[1][0], 0, 0, 0);
            acc[0][1] = __builtin_amdgcn_mfma_f32_16x16x32_bf16(afr[0][kt], c1, acc[0][1], 0, 0, 0);
            acc[1][1] = __builtin_amdgcn_mfma_f32_16x16x32_bf16(afr[1][kt], c1, acc[1][1], 0, 0, 0);
        }

        // bias (per output column)
        const float* bias = (st == 0) ? ba : (st == 1) ? bb : bs;
        float b0 = bias[eb * 128 + wc * 32 + l16];
        float b1 = bias[eb * 128 + wc * 32 + 16 + l16];
#pragma unroll
        for (int mt = 0; mt < 2; mt++)
#pragma unroll
            for (int r = 0; r < 4; r++) { acc[mt][0][r] += b0; acc[mt][1][r] += b1; }

        // gated fold. Gate table rows: a:0-15, b:16-31, s:32-55.
        // out_a = cat(ea,es): ea->e, es->8+e ; out_b = cat(eb,es): eb->16+e, es->24+e
        // out_s = cat(ea,eb,es): ea->32+e, eb->40+e, es->48+e
        if (st == 0)      { FOLD(0, 0);  FOLD(2, 32); }
        else if (st == 1) { FOLD(1, 16); FOLD(2, 40); }
        else              { FOLD(0, 8);  FOLD(1, 24); FOLD(2, 48); }

        // barrier: panel g fully consumed by all waves; panel g+1 DMA drained
        __syncthreads();
    }
#undef FOLD

    // ---- epilogue: store 3 outputs (full 128B lines per row) ----
#pragma unroll
    for (int oi = 0; oi < 3; oi++) {
        float* ob = out + (size_t)oi * BATCH * DDIM;
#pragma unroll
        for (int mt = 0; mt < 2; mt++)
#pragma unroll
            for (int r = 0; r < 4; r++) {
                int row = r0 + mb + mt * 16 + quad * 4 + r;
#pragma unroll
                for (int ntl = 0; ntl < 2; ntl++)
                    ob[(size_t)row * DDIM + wc * 32 + ntl * 16 + l16] = o[oi][mt][ntl][r];
            }
    }
}

extern "C" void kernel_launch(void* const* d_in, const int* in_sizes, int n_in,
                              void* d_out, int out_size, void* d_ws, size_t ws_size,
                              hipStream_t stream) {
    const float* xa = (const float*)d_in[0];
    const float* xb = (const float*)d_in[1];
    const float* xs = (const float*)d_in[2];
    const float* Wa = (const float*)d_in[3];
    const float* ba = (const float*)d_in[4];
    const float* Wb = (const float*)d_in[5];
    const float* bb = (const float*)d_in[6];
    const float* Ws = (const float*)d_in[7];
    const float* bs = (const float*)d_in[8];
    const float* Ga = (const float*)d_in[9];
    const float* Gb = (const float*)d_in[10];
    const float* Gs = (const float*)d_in[11];

    __bf16* wp = (__bf16*)d_ws;                 // 1.5 MB packed expert weights
    __bf16* gp = wp + 3 * 8 * 8 * 8 * 64 * 8;   // packed gate matrix

    prep_kernel<<<392, 256, 0, stream>>>(Wa, Wb, Ws, Ga, Gb, Gs, wp, gp);
    ple_kernel<<<BATCH / ROWS, 512, 0, stream>>>(xa, xb, xs, ba, bb, bs, wp, gp, (float*)d_out);
}